// Round 5
// baseline (75783.026 us; speedup 1.0000x reference)
//
#include <hip/hip_runtime.h>
#include <math.h>

#define B_ 64
#define L_ 512
#define H_ 512
#define D_ 80
#define NG 2048                      // 4*H
#define SCALE 0.044194173824159216f  // 1/sqrt(512)

// ---------------- persistent device scratch ---------------------------------
__device__ float g_K2[(size_t)B_ * L_ * H_];   // 67 MB   [b][l][m]
__device__ float g_V2[(size_t)B_ * L_ * D_];   // 10.5 MB [b][l][d]
__device__ float g_sb[B_ * L_];
__device__ float g_WqT[H_ * H_];
__device__ float g_Wkq[H_ * H_];
__device__ float g_Wv2[H_ * D_];
__device__ float g_bkq[H_];
__device__ float g_bv2[D_];
__device__ float g_wkb[H_];
__device__ float g_bias[NG];
__device__ float g_c0s;
__device__ float g_xT[H_ * B_];      // x transposed [k][b]
__device__ float g_hT[2][H_ * B_];   // h transposed, double-buffered
__device__ float g_hRM[B_ * H_];     // h row-major (for attention staging)
__device__ float g_cT[H_ * B_];      // c transposed
__device__ float g_e[B_ * L_];       // exp(scores)
__device__ float g_psum[B_ * 8];     // per-slice exp sums

// ---------------- small precompute kernels ---------------------------------
__global__ void k_prep_small(const float* __restrict__ Wq, const float* __restrict__ bk,
                             const float* __restrict__ bq, const float* __restrict__ Wk,
                             const float* __restrict__ bih, const float* __restrict__ bhh,
                             const float* __restrict__ bv, const float* __restrict__ W2) {
  __shared__ float red[256];
  int blk = blockIdx.x, tid = threadIdx.x;
  if (blk < 2) {                       // bkq[n] = sum_j bk[j] * Wq[n][j]
    int n = blk * 256 + tid;
    const float* wr = Wq + (size_t)n * H_;
    float s = 0.f;
    for (int j = 0; j < H_; ++j) s += bk[j] * wr[j];
    g_bkq[n] = s;
  } else if (blk < 4) {                // wkb[m] = sum_k Wk[m][k] * bq[k]
    int m = (blk - 2) * 256 + tid;
    const float* wr = Wk + (size_t)m * H_;
    float s = 0.f;
    for (int k = 0; k < H_; ++k) s += wr[k] * bq[k];
    g_wkb[m] = s;
  } else if (blk < 12) {               // bias = b_ih + b_hh
    int j = (blk - 4) * 256 + tid;
    g_bias[j] = bih[j] + bhh[j];
  } else if (blk == 12) {              // bv2[d] = sum_k bv[k] * W2[k][d]
    if (tid < D_) {
      float s = 0.f;
      for (int k = 0; k < H_; ++k) s += bv[k] * W2[(size_t)k * D_ + tid];
      g_bv2[tid] = s;
    }
  } else {                             // c0s = bk . bq
    float s = 0.f;
    for (int k = tid; k < H_; k += 256) s += bk[k] * bq[k];
    red[tid] = s; __syncthreads();
    for (int o = 128; o > 0; o >>= 1) { if (tid < o) red[tid] += red[tid + o]; __syncthreads(); }
    if (tid == 0) g_c0s = red[0];
  }
}

__global__ void k_transpose_wq(const float* __restrict__ Wq) {  // grid 1024
  int id = blockIdx.x * 256 + threadIdx.x;
  int j = id >> 9, n = id & (H_ - 1);
  g_WqT[(size_t)j * H_ + n] = Wq[(size_t)n * H_ + j];
}

// C = A @ B (+bias), tiled 64x64, K multiple of 32, M multiple of 64.
// which: 0 -> C=g_Wkq, B=g_WqT        1 -> C=g_Wv2, B=Bext(W2)
//        2 -> C=g_K2,  B=g_Wkq,+bkq   3 -> C=g_V2,  B=g_Wv2,+bv2
__global__ void __launch_bounds__(256) k_gemm(const float* __restrict__ A,
                                              const float* __restrict__ Bext,
                                              int which, int M, int N, int K) {
  __shared__ __align__(16) float As[32][68];
  __shared__ __align__(16) float Bs[32][68];
  const float* Bm; const float* bias; float* C;
  switch (which) {
    case 0:  Bm = g_WqT; bias = nullptr; C = g_Wkq; break;
    case 1:  Bm = Bext;  bias = nullptr; C = g_Wv2; break;
    case 2:  Bm = g_Wkq; bias = g_bkq;   C = g_K2;  break;
    default: Bm = g_Wv2; bias = g_bv2;   C = g_V2;  break;
  }
  int bm = blockIdx.x, bn = blockIdx.y, tid = threadIdx.x;
  int tm = (tid & 15) << 2, tn = (tid >> 4) << 2;
  float acc[4][4] = {};
  for (int k0 = 0; k0 < K; k0 += 32) {
    for (int i = tid; i < 64 * 32; i += 256) {
      int m = i >> 5, kk = i & 31;
      As[kk][m] = A[(size_t)(bm * 64 + m) * K + k0 + kk];
    }
    for (int i = tid; i < 32 * 64; i += 256) {
      int kk = i >> 6, n = i & 63;
      int gn = bn * 64 + n;
      Bs[kk][n] = (gn < N) ? Bm[(size_t)(k0 + kk) * N + gn] : 0.f;
    }
    __syncthreads();
#pragma unroll 8
    for (int kk = 0; kk < 32; ++kk) {
      float4 av = *(const float4*)&As[kk][tm];
      float4 bv = *(const float4*)&Bs[kk][tn];
      float a[4] = {av.x, av.y, av.z, av.w};
      float bb[4] = {bv.x, bv.y, bv.z, bv.w};
#pragma unroll
      for (int i2 = 0; i2 < 4; ++i2)
#pragma unroll
        for (int j2 = 0; j2 < 4; ++j2) acc[i2][j2] += a[i2] * bb[j2];
    }
    __syncthreads();
  }
#pragma unroll
  for (int i2 = 0; i2 < 4; ++i2) {
    int gm = bm * 64 + tm + i2;
#pragma unroll
    for (int j2 = 0; j2 < 4; ++j2) {
      int gn = bn * 64 + tn + j2;
      if (gn < N) C[(size_t)gm * N + gn] = acc[i2][j2] + (bias ? bias[gn] : 0.f);
    }
  }
}

__global__ void k_sb(const float* __restrict__ hid) {  // grid 1024
  __shared__ float wk[H_];
  int tid = threadIdx.x;
  for (int i = tid; i < H_; i += 256) wk[i] = g_wkb[i];
  __syncthreads();
  int wave = tid >> 6, lane = tid & 63;
  float c0s = g_c0s;
  int row0 = blockIdx.x * 32 + wave * 8;
  for (int r = 0; r < 8; ++r) {
    int row = row0 + r;
    const float* hr = hid + (size_t)row * H_;
    float s = 0.f;
#pragma unroll
    for (int j = 0; j < 8; ++j) { int k = lane + 64 * j; s += hr[k] * wk[k]; }
    for (int o = 32; o > 0; o >>= 1) s += __shfl_xor(s, o);
    if (lane == 0) g_sb[row] = s + c0s;
  }
}

__global__ void k_init(const float* __restrict__ h0, const float* __restrict__ c0,
                       const float* __restrict__ init_in, const float* __restrict__ W1,
                       const float* __restrict__ b1) {  // grid 256
  int blk = blockIdx.x, tid = threadIdx.x;
  if (blk < 128) {
    int id = blk * 256 + tid;           // 32768 = H*B
    int j = id >> 6, b = id & 63;
    g_hT[0][id] = h0[(size_t)b * H_ + j];
    g_cT[id]    = c0[(size_t)b * H_ + j];
  } else {
    int id = (blk - 128) * 256 + tid;   // 32768 = B*H
    int b = id >> 9, k = id & 511;
    const float* xi = init_in + (size_t)b * D_;
    float s = b1[k];
    for (int d = 0; d < D_; ++d) s += xi[d] * W1[(size_t)d * H_ + k];
    g_xT[(size_t)k * B_ + b] = fmaxf(s, 0.f);
  }
}

// ---------------- per-step kernels ------------------------------------------
// Phase A: gates + LSTM cell. 256 blocks, block handles 2 h-columns; wave g
// computes gate g for all 64 batches (coalesced reads of xT/hT [k][b]).
__global__ void __launch_bounds__(256) kA(const float* __restrict__ Wih,
                                          const float* __restrict__ Whh, int hp) {
  __shared__ float smg[4][B_];
  int blk = blockIdx.x, tid = threadIdx.x;
  int b = tid & 63, g = tid >> 6;
  const float* xT = g_xT;
  const float* hT = g_hT[hp];
  float* hTn = g_hT[hp ^ 1];
  for (int cc = 0; cc < 2; ++cc) {
    int col = blk * 2 + cc;
    int j = g * H_ + col;
    const float* wi = Wih + (size_t)j * H_;
    const float* wh = Whh + (size_t)j * H_;
    float ax0 = 0.f, ax1 = 0.f, ah0 = 0.f, ah1 = 0.f;
#pragma unroll 8
    for (int k = 0; k < H_; k += 2) {
      ax0 += xT[k * B_ + b] * wi[k];
      ah0 += hT[k * B_ + b] * wh[k];
      ax1 += xT[(k + 1) * B_ + b] * wi[k + 1];
      ah1 += hT[(k + 1) * B_ + b] * wh[k + 1];
    }
    smg[g][b] = g_bias[j] + ((ax0 + ax1) + (ah0 + ah1));
    __syncthreads();
    if (g == 0) {
      float iv = smg[0][b], fv = smg[1][b], gv = smg[2][b], ov = smg[3][b];
      float co = g_cT[col * B_ + b];
      float si = 1.f / (1.f + expf(-iv));
      float sf = 1.f / (1.f + expf(-fv));
      float so = 1.f / (1.f + expf(-ov));
      float cn = sf * co + si * tanhf(gv);
      float hn = so * tanhf(cn);
      g_cT[col * B_ + b] = cn;
      hTn[col * B_ + b]  = hn;
      g_hRM[(size_t)b * H_ + col] = hn;
    }
    __syncthreads();
  }
}

// Phase C: scores + exp + partial sums. 512 blocks: (b, 64-row l-slice).
__global__ void __launch_bounds__(256) kC(const int* __restrict__ mask) {
  __shared__ __align__(16) float hs[H_];
  __shared__ float ps[4];
  int blk = blockIdx.x, tid = threadIdx.x;
  int b = blk >> 3, sub = blk & 7;
  for (int i = tid; i < H_; i += 256) hs[i] = g_hRM[(size_t)b * H_ + i];
  __syncthreads();
  int wave = tid >> 6, lane = tid & 63;
  const float* K2b = g_K2 + (size_t)b * L_ * H_;
  float4 h0 = *(const float4*)&hs[lane * 4];
  float4 h1 = *(const float4*)&hs[256 + lane * 4];
  float lsum = 0.f;
  int lbase = sub * 64 + wave * 16;
  for (int rg = 0; rg < 4; ++rg) {
    int l = lbase + rg * 4;
    float s[4];
#pragma unroll
    for (int r = 0; r < 4; ++r) {
      const float* rp = K2b + (size_t)(l + r) * H_ + lane * 4;
      float4 a0 = *(const float4*)rp;
      float4 a1 = *(const float4*)(rp + 256);
      s[r] = a0.x * h0.x + a0.y * h0.y + a0.z * h0.z + a0.w * h0.w
           + a1.x * h1.x + a1.y * h1.y + a1.z * h1.z + a1.w * h1.w;
    }
#pragma unroll
    for (int r = 0; r < 4; ++r) {
      float v = s[r];
      for (int o = 32; o > 0; o >>= 1) v += __shfl_xor(v, o);
      if (lane == 0) {
        int li = l + r;
        float sc = (v + g_sb[b * L_ + li]) * SCALE;
        float e = mask[b * L_ + li] ? expf(sc) : 0.f;   // mask is int32 (bool->int)
        g_e[b * L_ + li] = e;
        lsum += e;
      }
    }
  }
  if (lane == 0) ps[wave] = lsum;
  __syncthreads();
  if (tid == 0) g_psum[b * 8 + sub] = ps[0] + ps[1] + ps[2] + ps[3];
}

// Phase DEF: per-batch block: softmax finalize + attn write + out + next x.
__global__ void __launch_bounds__(256) kDEF(int t, const float* __restrict__ W1,
                                            const float* __restrict__ b1,
                                            const float* __restrict__ b2,
                                            float* __restrict__ out) {
  __shared__ float at[L_];
  __shared__ float ot[D_];
  int b = blockIdx.x, tid = threadIdx.x;
  float S = 0.f;
#pragma unroll
  for (int i = 0; i < 8; ++i) S += g_psum[b * 8 + i];
  float inv = (S > 0.f) ? 1.f / S : 0.f;
  bool uni = !(S > 0.f);
  float* attn_out = out + (size_t)B_ * L_ * D_ + ((size_t)b * L_ + t) * L_;
  for (int l = tid; l < L_; l += 256) {
    float a = uni ? (1.f / L_) : g_e[b * L_ + l] * inv;
    at[l] = a;
    attn_out[l] = a;
  }
  __syncthreads();
  if (tid < D_) {
    const float* V2b = g_V2 + (size_t)b * L_ * D_ + tid;
    float a0 = 0.f, a1 = 0.f, a2 = 0.f, a3 = 0.f;
    for (int l = 0; l < L_; l += 4) {
      a0 += at[l]     * V2b[(size_t)l * D_];
      a1 += at[l + 1] * V2b[(size_t)(l + 1) * D_];
      a2 += at[l + 2] * V2b[(size_t)(l + 2) * D_];
      a3 += at[l + 3] * V2b[(size_t)(l + 3) * D_];
    }
    float acc = b2[tid] + ((a0 + a1) + (a2 + a3));
    ot[tid] = acc;
    out[((size_t)b * L_ + t) * D_ + tid] = acc;
  }
  __syncthreads();
  for (int k = tid; k < H_; k += 256) {
    float xv = b1[k];
#pragma unroll 8
    for (int d = 0; d < D_; ++d) xv += ot[d] * W1[(size_t)d * H_ + k];
    g_xT[(size_t)k * B_ + b] = fmaxf(xv, 0.f);
  }
}

// ---------------- launch ----------------------------------------------------
extern "C" void kernel_launch(void* const* d_in, const int* in_sizes, int n_in,
                              void* d_out, int out_size, void* d_ws, size_t ws_size,
                              hipStream_t stream) {
  const float* hid  = (const float*)d_in[0];
  const int* mask = (const int*)d_in[1];
  const float* init_in = (const float*)d_in[2];
  const float* h0 = (const float*)d_in[3];
  const float* c0 = (const float*)d_in[4];
  const float* W1 = (const float*)d_in[5];
  const float* b1 = (const float*)d_in[6];
  const float* Wih = (const float*)d_in[7];
  const float* Whh = (const float*)d_in[8];
  const float* bih = (const float*)d_in[9];
  const float* bhh = (const float*)d_in[10];
  const float* Wq = (const float*)d_in[11];
  const float* bq = (const float*)d_in[12];
  const float* Wk = (const float*)d_in[13];
  const float* bk = (const float*)d_in[14];
  const float* Wv = (const float*)d_in[15];
  const float* bv = (const float*)d_in[16];
  const float* W2 = (const float*)d_in[17];
  const float* b2 = (const float*)d_in[18];
  float* out = (float*)d_out;

  k_prep_small<<<14, 256, 0, stream>>>(Wq, bk, bq, Wk, bih, bhh, bv, W2);
  k_transpose_wq<<<1024, 256, 0, stream>>>(Wq);
  k_gemm<<<dim3(8, 8), 256, 0, stream>>>(Wk, nullptr, 0, 512, 512, 512);      // Wkq
  k_gemm<<<dim3(8, 2), 256, 0, stream>>>(Wv, W2, 1, 512, 80, 512);            // Wv2
  k_gemm<<<dim3(512, 8), 256, 0, stream>>>(hid, nullptr, 2, 32768, 512, 512); // K2
  k_gemm<<<dim3(512, 2), 256, 0, stream>>>(hid, nullptr, 3, 32768, 80, 512);  // V2
  k_sb<<<1024, 256, 0, stream>>>(hid);
  k_init<<<256, 256, 0, stream>>>(h0, c0, init_in, W1, b1);

  for (int t = 0; t < L_; ++t) {
    kA<<<256, 256, 0, stream>>>(Wih, Whh, t & 1);
    kC<<<512, 256, 0, stream>>>(mask);
    kDEF<<<64, 256, 0, stream>>>(t, W1, b1, b2, out);
  }
}